// Round 6
// baseline (391.962 us; speedup 1.0000x reference)
//
#include <hip/hip_runtime.h>

typedef __bf16 bf16x8 __attribute__((ext_vector_type(8)));
typedef float  f32x4  __attribute__((ext_vector_type(4)));

#define KDIM    784
#define KSTEP   32
#define NSTEPS  25          // ceil(784/32) -> K padded to 800
#define NCOLS   128
#define NT      8           // 128 / 16 col-tiles
#define WAVES   4
#define ROWS_PER_WAVE 32
#define ROWS_PER_BLOCK (WAVES * ROWS_PER_WAVE)   // 128
#define STAGE_BYTES 16384   // 2 k-steps of B-frags: 2 * 8 frags * 64 lanes * 16 B
#define HSH_PAD 132
#define HCHUNK  16          // fc2 processes 16 rows per m-chunk
#define PREP_BLOCKS 50      // 50 blocks x 256 threads = 12800 items
#define FLAG_MAGIC 0x5EEDF00Du

__device__ __forceinline__ bf16x8 pack8(f32x4 lo, f32x4 hi) {
  bf16x8 r;
  r[0] = (__bf16)lo[0]; r[1] = (__bf16)lo[1];
  r[2] = (__bf16)lo[2]; r[3] = (__bf16)lo[3];
  r[4] = (__bf16)hi[0]; r[5] = (__bf16)hi[1];
  r[6] = (__bf16)hi[2]; r[7] = (__bf16)hi[3];
  return r;
}

// Split 8 fp32 into bf16 hi + bf16 residual lo (hi+lo reproduces fp32 to ~2^-17)
__device__ __forceinline__ void split8(f32x4 a, f32x4 b, bf16x8& hi, bf16x8& lo) {
#pragma unroll
  for (int j = 0; j < 4; ++j) {
    __bf16 h = (__bf16)a[j]; hi[j] = h; lo[j] = (__bf16)(a[j] - (float)h);
  }
#pragma unroll
  for (int j = 0; j < 4; ++j) {
    __bf16 h = (__bf16)b[j]; hi[4 + j] = h; lo[4 + j] = (__bf16)(b[j] - (float)h);
  }
}

// Async global->LDS copy of one B-frag stage slice. dest is linear
// (wave-uniform base + lane*16) which matches the frag consumption layout.
__device__ __forceinline__ void stage_issue(
    const __bf16* __restrict__ wfrag, unsigned char* dstbuf,
    int stage, int wave, int lane, int nchunks)
{
#pragma unroll
  for (int c = 0; c < 4; ++c) {
    int cw = wave * 4 + c;
    if (cw < nchunks) {
      const unsigned char* src =
          (const unsigned char*)wfrag + (size_t)stage * STAGE_BYTES + cw * 1024 + lane * 16;
      unsigned char* dst = dstbuf + cw * 1024 + lane * 16;
      __builtin_amdgcn_global_load_lds(
          (const __attribute__((address_space(1))) unsigned int*)src,
          (__attribute__((address_space(3))) unsigned int*)dst,
          16, 0, 0);
    }
  }
}

// ---------------------------------------------------------------------------
// Single regular kernel (graph-capture safe):
//   blocks 0..49: compute Weff B-frags (1 item/thread, same math as the old
//     prep kernel), then __syncthreads + per-block agent-release flag store.
//   all 512 blocks: prefetch x(0) in regs, spin-gate on the 50 flags
//     (agent-acquire), then run the round-2 fused body verbatim.
// Deadlock-free: grid 512 = 2 blocks/CU capacity (33 KB LDS, <=256 VGPR) so
// producers are always resident; graph replays re-prep idempotently.
// ---------------------------------------------------------------------------
__global__ __launch_bounds__(256, 2) void fused_all(
    const float*  __restrict__ x,
    const float*  __restrict__ conv_w,
    const float*  __restrict__ fc1_w,
    const float*  __restrict__ fc1_b,
    const float*  __restrict__ fc2_w,
    const float*  __restrict__ fc2_b,
    float*        __restrict__ out,
    unsigned int* __restrict__ flags,
    __bf16*       __restrict__ wfrag)
{
  // 33 KiB: per-wave 16-row fc2 chunk buffers; first 32 KiB double as the two
  // B-frag staging buffers (dead before hsh is first written; barrier-separated).
  __shared__ __align__(16) unsigned char smem[WAVES * HCHUNK * HSH_PAD * 4];
  float (*hsh)[HCHUNK][HSH_PAD] =
      reinterpret_cast<float (*)[HCHUNK][HSH_PAD]>(smem);

  int tid  = threadIdx.x;
  int wave = tid >> 6, lane = tid & 63;
  int lrow = lane & 15;      // A row within 16-tile / B col within 16-tile
  int lgrp = lane >> 4;      // k sub-group
  long wrow0 = (long)blockIdx.x * ROWS_PER_BLOCK + wave * ROWS_PER_WAVE;

  const float* xr0 = x + (wrow0 + lrow) * KDIM;
  const float* xr1 = xr0 + 16 * KDIM;

  // x pipeline registers: one full stage (2 k-steps) ahead
  f32x4 xv[8];
#define LOAD_STAGE(T)                                          \
  {                                                            \
    int k0 = (2 * (T)) * KSTEP + lgrp * 8;                     \
    xv[0] = *(const f32x4*)(xr0 + k0);                         \
    xv[1] = *(const f32x4*)(xr0 + k0 + 4);                     \
    xv[2] = *(const f32x4*)(xr1 + k0);                         \
    xv[3] = *(const f32x4*)(xr1 + k0 + 4);                     \
    xv[4] = *(const f32x4*)(xr0 + k0 + KSTEP);                 \
    xv[5] = *(const f32x4*)(xr0 + k0 + KSTEP + 4);             \
    xv[6] = *(const f32x4*)(xr1 + k0 + KSTEP);                 \
    xv[7] = *(const f32x4*)(xr1 + k0 + KSTEP + 4);             \
  }

  // ---- issue x(0) prefetch first: no wfrag dependency, hides prep ---------
  LOAD_STAGE(0);

  // ---- phase 1: Weff prep on blocks 0..49 (1 item/thread) -----------------
  if (blockIdx.x < PREP_BLOCKS) {
    int idx  = blockIdx.x * 256 + tid;               // < 12800
    int plane = idx & 63;
    int n    = (idx >> 6) & (NT - 1);
    int s    = idx >> 9;
    int col  = n * 16 + (plane & 15);
    int kb   = s * KSTEP + (plane >> 4) * 8;
    bf16x8 o;
#pragma unroll
    for (int j = 0; j < 8; ++j) {
      int k = kb + j;
      float v = 0.f;
      if (k < KDIM) {
        int r = k / 28, c = k % 28;
#pragma unroll
        for (int u = 0; u < 3; ++u)
#pragma unroll
          for (int w = 0; w < 3; ++w) {
            int p = r - u, q = c - w;
            if (p >= 0 && p < 26 && q >= 0 && q < 26)
              v = fmaf(conv_w[u * 3 + w], fc1_w[col * 676 + p * 26 + q], v);
          }
      }
      o[j] = (__bf16)v;
    }
    reinterpret_cast<bf16x8*>(wfrag)[idx] = o;
    __syncthreads();   // all of this block's wfrag stores issued
    if (tid == 0)      // release: wbl2 pushes the block's lines to coherent point
      __hip_atomic_store(&flags[blockIdx.x], FLAG_MAGIC ^ blockIdx.x,
                         __ATOMIC_RELEASE, __HIP_MEMORY_SCOPE_AGENT);
  }

  // ---- gate: wait for all 50 producer blocks (parallel acquire polls) -----
  if (tid < PREP_BLOCKS) {
    while (__hip_atomic_load(&flags[tid], __ATOMIC_ACQUIRE,
                             __HIP_MEMORY_SCOPE_AGENT) != (FLAG_MAGIC ^ (unsigned)tid)) {}
  }
  __syncthreads();     // whole block sees coherent wfrag (acquire inv'd caches)

  f32x4 acc[2][NT];
#pragma unroll
  for (int m = 0; m < 2; ++m)
#pragma unroll
    for (int n = 0; n < NT; ++n) acc[m][n] = (f32x4){0.f, 0.f, 0.f, 0.f};

  // ---- prologue: stage 0 B-frags ------------------------------------------
  stage_issue(wfrag, smem, 0, wave, lane, 16);
  int cur = 0;

  // ---- K loop: 12 stages of 2 steps (s=0..23); tail (s=24) after ----------
  for (int t = 0; t < 12; ++t) {
    __syncthreads();   // stage(t) B-frags landed (vmcnt drain); prev reads done
    stage_issue(wfrag, smem + (cur ^ 1) * STAGE_BYTES, t + 1, wave, lane,
                (t < 11) ? 16 : 8);

    // pack current-stage A fragments, freeing xv for the next prefetch
    bf16x8 a00 = pack8(xv[0], xv[1]), a01 = pack8(xv[2], xv[3]);
    bf16x8 a10 = pack8(xv[4], xv[5]), a11 = pack8(xv[6], xv[7]);

    // prefetch x for stage t+1 (tail: only k<784 lanes real, rest zero)
    if (t < 11) {
      LOAD_STAGE(t + 1);
    } else {
      if (lgrp < 2) {
        int k = (NSTEPS - 1) * KSTEP + lgrp * 8;   // 768 or 776
        xv[0] = *(const f32x4*)(xr0 + k);
        xv[1] = *(const f32x4*)(xr0 + k + 4);
        xv[2] = *(const f32x4*)(xr1 + k);
        xv[3] = *(const f32x4*)(xr1 + k + 4);
      } else {
        xv[0] = (f32x4){0.f,0.f,0.f,0.f}; xv[1] = (f32x4){0.f,0.f,0.f,0.f};
        xv[2] = (f32x4){0.f,0.f,0.f,0.f}; xv[3] = (f32x4){0.f,0.f,0.f,0.f};
      }
    }

    const bf16x8* bp = (const bf16x8*)(smem + cur * STAGE_BYTES) + lane;
    {
      bf16x8 bf[NT];
#pragma unroll
      for (int n = 0; n < NT; ++n) bf[n] = bp[n * 64];
#pragma unroll
      for (int n = 0; n < NT; ++n) {
        acc[0][n] = __builtin_amdgcn_mfma_f32_16x16x32_bf16(a00, bf[n], acc[0][n], 0, 0, 0);
        acc[1][n] = __builtin_amdgcn_mfma_f32_16x16x32_bf16(a01, bf[n], acc[1][n], 0, 0, 0);
      }
    }
    {
      bf16x8 bf[NT];
#pragma unroll
      for (int n = 0; n < NT; ++n) bf[n] = bp[512 + n * 64];
#pragma unroll
      for (int n = 0; n < NT; ++n) {
        acc[0][n] = __builtin_amdgcn_mfma_f32_16x16x32_bf16(a10, bf[n], acc[0][n], 0, 0, 0);
        acc[1][n] = __builtin_amdgcn_mfma_f32_16x16x32_bf16(a11, bf[n], acc[1][n], 0, 0, 0);
      }
    }
    cur ^= 1;
  }

  // ---- tail step s = 24 (x already in xv[0..3]) ---------------------------
  __syncthreads();   // tail stage landed
  {
    bf16x8 a0 = pack8(xv[0], xv[1]);
    bf16x8 a1 = pack8(xv[2], xv[3]);
    const bf16x8* bp = (const bf16x8*)(smem + cur * STAGE_BYTES) + lane;
#pragma unroll
    for (int n = 0; n < NT; ++n) {
      bf16x8 b = bp[n * 64];
      acc[0][n] = __builtin_amdgcn_mfma_f32_16x16x32_bf16(a0, b, acc[0][n], 0, 0, 0);
      acc[1][n] = __builtin_amdgcn_mfma_f32_16x16x32_bf16(a1, b, acc[1][n], 0, 0, 0);
    }
  }
  __syncthreads();   // all staging reads done before hsh overwrites the buffers

  // ---- fc2 B-fragments from fc2_w (L2-resident), hi/lo split --------------
  // B-frag: col(lane&15)=o, k=(lane>>4)*8+j
  int osafe = (lrow < 10) ? lrow : 9;
  bf16x8 whi[4], wlo[4];
#pragma unroll
  for (int s2 = 0; s2 < 4; ++s2) {
    f32x4 w0 = *(const f32x4*)(fc2_w + osafe * NCOLS + s2 * 32 + lgrp * 8);
    f32x4 w1 = *(const f32x4*)(fc2_w + osafe * NCOLS + s2 * 32 + lgrp * 8 + 4);
    if (lrow >= 10) { w0 = (f32x4){0.f,0.f,0.f,0.f}; w1 = (f32x4){0.f,0.f,0.f,0.f}; }
    split8(w0, w1, whi[s2], wlo[s2]);
  }
  float b2 = (lrow < 10) ? fc2_b[lrow] : 0.f;
  float bcol[NT];
#pragma unroll
  for (int n = 0; n < NT; ++n) bcol[n] = fc1_b[n * 16 + lrow];

  // ---- epilogue in two 16-row chunks: bias+relu -> LDS -> fc2 MFMA --------
  // fc1 C/D layout (m89): col = lane&15, row = (lane>>4)*4 + reg_idx.
  // hsh[wave] is per-wave private: same-wave LDS RAW handled by lgkmcnt.
#pragma unroll
  for (int m2 = 0; m2 < 2; ++m2) {
#pragma unroll
    for (int n = 0; n < NT; ++n) {
      int col = n * 16 + lrow;
#pragma unroll
      for (int ri = 0; ri < 4; ++ri) {
        int rl = lgrp * 4 + ri;
        hsh[wave][rl][col] = fmaxf(acc[m2][n][ri] + bcol[n], 0.f);
      }
    }
    f32x4 acc2 = (f32x4){0.f, 0.f, 0.f, 0.f};
    const float* hr = &hsh[wave][lrow][0];
#pragma unroll
    for (int s2 = 0; s2 < 4; ++s2) {
      f32x4 h0 = *(const f32x4*)(hr + s2 * 32 + lgrp * 8);
      f32x4 h1 = *(const f32x4*)(hr + s2 * 32 + lgrp * 8 + 4);
      bf16x8 ahi, alo; split8(h0, h1, ahi, alo);
      acc2 = __builtin_amdgcn_mfma_f32_16x16x32_bf16(ahi, whi[s2], acc2, 0, 0, 0);
      acc2 = __builtin_amdgcn_mfma_f32_16x16x32_bf16(ahi, wlo[s2], acc2, 0, 0, 0);
      acc2 = __builtin_amdgcn_mfma_f32_16x16x32_bf16(alo, whi[s2], acc2, 0, 0, 0);
    }
    // D layout: col(lane&15)=o, row=(lane>>4)*4+reg -> rows m2*16+lgrp*4+ri
    if (lrow < 10) {
#pragma unroll
      for (int ri = 0; ri < 4; ++ri)
        out[(wrow0 + m2 * 16 + lgrp * 4 + ri) * 10 + lrow] = acc2[ri] + b2;
    }
  }
}

extern "C" void kernel_launch(void* const* d_in, const int* in_sizes, int n_in,
                              void* d_out, int out_size, void* d_ws, size_t ws_size,
                              hipStream_t stream) {
  const float* x      = (const float*)d_in[0];
  const float* conv_w = (const float*)d_in[1];
  const float* fc1_w  = (const float*)d_in[2];
  const float* fc1_b  = (const float*)d_in[3];
  const float* fc2_w  = (const float*)d_in[4];
  const float* fc2_b  = (const float*)d_in[5];
  float* outp = (float*)d_out;

  // workspace layout: [0,512): flags (50 u32 + pad), [512, 512+204800): wfrag
  unsigned int* flags = (unsigned int*)d_ws;
  __bf16* wfrag = (__bf16*)((char*)d_ws + 512);

  int Btotal = in_sizes[0] / KDIM;              // 65536
  dim3 grid(Btotal / ROWS_PER_BLOCK);           // 512 = 2 blocks/CU

  hipLaunchKernelGGL(fused_all, grid, dim3(256), 0, stream,
                     x, conv_w, fc1_w, fc1_b, fc2_w, fc2_b, outp, flags, wfrag);
}

// Round 7
// 51.761 us; speedup vs baseline: 7.5726x; 7.5726x over previous
//
#include <hip/hip_runtime.h>

typedef __bf16 bf16x8 __attribute__((ext_vector_type(8)));
typedef float  f32x4  __attribute__((ext_vector_type(4)));

#define KDIM    784
#define KSTEP   32
#define NSTEPS  25          // ceil(784/32) -> K padded to 800
#define NCOLS   128
#define NT      8           // 128 / 16 col-tiles
#define WAVES   4
#define ROWS_PER_WAVE 32
#define ROWS_PER_BLOCK (WAVES * ROWS_PER_WAVE)   // 128
#define KSTEP_BYTES 8192    // one k-step of B-frags: 8 frags * 64 lanes * 16 B
#define STAGE_BYTES 32768   // 4 k-steps per stage (BK=128)
#define NFULL   6           // 6 full stages cover k-steps 0..23; tail = step 24
#define HSH_PAD 132
#define HCHUNK  16          // fc2 processes 16 rows per m-chunk

// ---------------------------------------------------------------------------
// Prep: Weff[j,k] = sum_{u,v} conv_w[u,v] * fc1_w[j,(r-u)*26+(c-v)], stored as
// bf16 MFMA B-fragments: wfrag[((s*NT + n)*64 + lane)*8 + j] holds
// Weff[col = n*16 + (lane&15)][k = s*32 + (lane>>4)*8 + j]   (0 if k >= 784).
// ---------------------------------------------------------------------------
__global__ __launch_bounds__(256) void prep_weff(
    const float* __restrict__ conv_w,
    const float* __restrict__ fc1_w,
    __bf16* __restrict__ wfrag)
{
  int idx = blockIdx.x * 256 + threadIdx.x;
  if (idx >= NSTEPS * NT * 64) return;
  int lane = idx & 63;
  int n    = (idx >> 6) & (NT - 1);
  int s    = idx >> 9;
  int col  = n * 16 + (lane & 15);
  int kb   = s * KSTEP + (lane >> 4) * 8;
  bf16x8 o;
#pragma unroll
  for (int j = 0; j < 8; ++j) {
    int k = kb + j;
    float v = 0.f;
    if (k < KDIM) {
      int r = k / 28, c = k % 28;
#pragma unroll
      for (int u = 0; u < 3; ++u)
#pragma unroll
        for (int w = 0; w < 3; ++w) {
          int p = r - u, q = c - w;
          if (p >= 0 && p < 26 && q >= 0 && q < 26)
            v = fmaf(conv_w[u * 3 + w], fc1_w[col * 676 + p * 26 + q], v);
        }
    }
    o[j] = (__bf16)v;
  }
  reinterpret_cast<bf16x8*>(wfrag)[idx] = o;
}

__device__ __forceinline__ bf16x8 pack8(f32x4 lo, f32x4 hi) {
  bf16x8 r;
  r[0] = (__bf16)lo[0]; r[1] = (__bf16)lo[1];
  r[2] = (__bf16)lo[2]; r[3] = (__bf16)lo[3];
  r[4] = (__bf16)hi[0]; r[5] = (__bf16)hi[1];
  r[6] = (__bf16)hi[2]; r[7] = (__bf16)hi[3];
  return r;
}

// Split 8 fp32 into bf16 hi + bf16 residual lo (hi+lo reproduces fp32 to ~2^-17)
__device__ __forceinline__ void split8(f32x4 a, f32x4 b, bf16x8& hi, bf16x8& lo) {
#pragma unroll
  for (int j = 0; j < 4; ++j) {
    __bf16 h = (__bf16)a[j]; hi[j] = h; lo[j] = (__bf16)(a[j] - (float)h);
  }
#pragma unroll
  for (int j = 0; j < 4; ++j) {
    __bf16 h = (__bf16)b[j]; hi[4 + j] = h; lo[4 + j] = (__bf16)(b[j] - (float)h);
  }
}

// Async global->LDS copy of one B-frag stage slice (cpw 1-KiB chunks per wave).
// dest is linear (wave-uniform base + lane*16), matching consumption layout.
__device__ __forceinline__ void stage_issue(
    const __bf16* __restrict__ wfrag, size_t src_off, unsigned char* dstbuf,
    int wave, int lane, int cpw)
{
#pragma unroll
  for (int c = 0; c < 8; ++c) {
    if (c < cpw) {
      int cw = wave * cpw + c;
      const unsigned char* src =
          (const unsigned char*)wfrag + src_off + cw * 1024 + lane * 16;
      unsigned char* dst = dstbuf + cw * 1024 + lane * 16;
      __builtin_amdgcn_global_load_lds(
          (const __attribute__((address_space(1))) unsigned int*)src,
          (__attribute__((address_space(3))) unsigned int*)dst,
          16, 0, 0);
    }
  }
}

// ---------------------------------------------------------------------------
// Main: per block 4 waves x 32 rows = 128 rows, all 128 h-columns via MFMA.
// BK=128 stages (4 k-steps) -> only 7 block-wide sync points (vs 13 at BK=64):
// halves the vmcnt(0) queue-drain stalls, and each stage has ~64 MFMAs of
// compute to hide x-load latency within the stage. B-frags double-buffered
// via global_load_lds; x loaded in two half-stage register batches (xvA/xvB).
// fc2 (128->10) via hi/lo-split bf16 MFMA in two 16-row chunks.
// ---------------------------------------------------------------------------
__global__ __launch_bounds__(256, 2) void fused_mlp(
    const float*  __restrict__ x,
    const __bf16* __restrict__ wfrag,
    const float*  __restrict__ fc1_b,
    const float*  __restrict__ fc2_w,
    const float*  __restrict__ fc2_b,
    float*        __restrict__ out)
{
  // 64 KiB: two BK=128 staging buffers; hsh (33 KiB) aliases the same space
  // (staging is dead before hsh is first written; barrier-separated).
  __shared__ __align__(16) unsigned char smem[2 * STAGE_BYTES];
  float (*hsh)[HCHUNK][HSH_PAD] =
      reinterpret_cast<float (*)[HCHUNK][HSH_PAD]>(smem);

  int tid  = threadIdx.x;
  int wave = tid >> 6, lane = tid & 63;
  int lrow = lane & 15;      // A row within 16-tile / B col within 16-tile
  int lgrp = lane >> 4;      // k sub-group
  long wrow0 = (long)blockIdx.x * ROWS_PER_BLOCK + wave * ROWS_PER_WAVE;

  const float* xr0 = x + (wrow0 + lrow) * KDIM;
  const float* xr1 = xr0 + 16 * KDIM;

  f32x4 acc[2][NT];
#pragma unroll
  for (int m = 0; m < 2; ++m)
#pragma unroll
    for (int n = 0; n < NT; ++n) acc[m][n] = (f32x4){0.f, 0.f, 0.f, 0.f};

  // x registers: two half-stage batches (2 k-steps x 2 rows = 8 f32x4 each)
  f32x4 xvA[8], xvB[8];
#define LOAD_X2(E, V)                                          \
  {                                                            \
    int k0 = (E) * KSTEP + lgrp * 8;                           \
    V[0] = *(const f32x4*)(xr0 + k0);                          \
    V[1] = *(const f32x4*)(xr0 + k0 + 4);                      \
    V[2] = *(const f32x4*)(xr1 + k0);                          \
    V[3] = *(const f32x4*)(xr1 + k0 + 4);                      \
    V[4] = *(const f32x4*)(xr0 + k0 + KSTEP);                  \
    V[5] = *(const f32x4*)(xr0 + k0 + KSTEP + 4);              \
    V[6] = *(const f32x4*)(xr1 + k0 + KSTEP);                  \
    V[7] = *(const f32x4*)(xr1 + k0 + KSTEP + 4);              \
  }

// one 2-k-step MFMA group: k-steps at byte offsets O0,O1 in buf, x regs V
#define MFMA_GROUP(BASE, O0, O1, V)                                            \
  {                                                                            \
    bf16x8 a00 = pack8(V[0], V[1]), a01 = pack8(V[2], V[3]);                   \
    bf16x8 a10 = pack8(V[4], V[5]), a11 = pack8(V[6], V[7]);                   \
    const bf16x8* bp0 = (const bf16x8*)((BASE) + (O0)) + lane;                 \
    {                                                                          \
      bf16x8 bf[NT];                                                           \
      _Pragma("unroll")                                                        \
      for (int n = 0; n < NT; ++n) bf[n] = bp0[n * 64];                        \
      _Pragma("unroll")                                                        \
      for (int n = 0; n < NT; ++n) {                                           \
        acc[0][n] = __builtin_amdgcn_mfma_f32_16x16x32_bf16(a00, bf[n], acc[0][n], 0, 0, 0); \
        acc[1][n] = __builtin_amdgcn_mfma_f32_16x16x32_bf16(a01, bf[n], acc[1][n], 0, 0, 0); \
      }                                                                        \
    }                                                                          \
    const bf16x8* bp1 = (const bf16x8*)((BASE) + (O1)) + lane;                 \
    {                                                                          \
      bf16x8 bf[NT];                                                           \
      _Pragma("unroll")                                                        \
      for (int n = 0; n < NT; ++n) bf[n] = bp1[n * 64];                        \
      _Pragma("unroll")                                                        \
      for (int n = 0; n < NT; ++n) {                                           \
        acc[0][n] = __builtin_amdgcn_mfma_f32_16x16x32_bf16(a10, bf[n], acc[0][n], 0, 0, 0); \
        acc[1][n] = __builtin_amdgcn_mfma_f32_16x16x32_bf16(a11, bf[n], acc[1][n], 0, 0, 0); \
      }                                                                        \
    }                                                                          \
  }

  // ---- prologue: stage 0 B-frags (32 KiB) + x for k-steps 0,1 -------------
  stage_issue(wfrag, 0, smem, wave, lane, 8);
  LOAD_X2(0, xvA);
  int cur = 0;

  // ---- K loop: 6 stages of 4 k-steps (s=0..23); tail (s=24) after ---------
  for (int t = 0; t < NFULL; ++t) {
    __syncthreads();   // stage(t) B-frags + this wave's x landed (vmcnt drain)

    // issue next stage's B-frags (tail stage at t=5: one k-step, 8 KiB)
    if (t < NFULL - 1)
      stage_issue(wfrag, (size_t)(t + 1) * STAGE_BYTES,
                  smem + (cur ^ 1) * STAGE_BYTES, wave, lane, 8);
    else
      stage_issue(wfrag, (size_t)24 * KSTEP_BYTES,
                  smem + (cur ^ 1) * STAGE_BYTES, wave, lane, 2);

    // x for second half of this stage (k-steps 4t+2, 4t+3): consumed ~32
    // MFMAs later -> latency hidden within the stage
    LOAD_X2(4 * t + 2, xvB);

    unsigned char* base = smem + cur * STAGE_BYTES;
    // first half: k-steps 4t, 4t+1 (xvA arrived before the barrier)
    MFMA_GROUP(base, 0 * KSTEP_BYTES, 1 * KSTEP_BYTES, xvA);

    // prefetch xvA for the next stage (or the tail k-step at t=5)
    if (t < NFULL - 1) {
      LOAD_X2(4 * t + 4, xvA);
    } else {
      if (lgrp < 2) {
        int k = 24 * KSTEP + lgrp * 8;   // 768 or 776 (< 784 real)
        xvA[0] = *(const f32x4*)(xr0 + k);
        xvA[1] = *(const f32x4*)(xr0 + k + 4);
        xvA[2] = *(const f32x4*)(xr1 + k);
        xvA[3] = *(const f32x4*)(xr1 + k + 4);
      } else {
        xvA[0] = (f32x4){0.f,0.f,0.f,0.f}; xvA[1] = (f32x4){0.f,0.f,0.f,0.f};
        xvA[2] = (f32x4){0.f,0.f,0.f,0.f}; xvA[3] = (f32x4){0.f,0.f,0.f,0.f};
      }
    }

    // second half: k-steps 4t+2, 4t+3
    MFMA_GROUP(base, 2 * KSTEP_BYTES, 3 * KSTEP_BYTES, xvB);
    cur ^= 1;
  }

  // ---- tail k-step s = 24 (x already in xvA[0..3]) ------------------------
  __syncthreads();   // tail stage landed
  {
    bf16x8 a0 = pack8(xvA[0], xvA[1]);
    bf16x8 a1 = pack8(xvA[2], xvA[3]);
    const bf16x8* bp = (const bf16x8*)(smem + cur * STAGE_BYTES) + lane;
#pragma unroll
    for (int n = 0; n < NT; ++n) {
      bf16x8 b = bp[n * 64];
      acc[0][n] = __builtin_amdgcn_mfma_f32_16x16x32_bf16(a0, b, acc[0][n], 0, 0, 0);
      acc[1][n] = __builtin_amdgcn_mfma_f32_16x16x32_bf16(a1, b, acc[1][n], 0, 0, 0);
    }
  }
  __syncthreads();   // all staging reads done before hsh overwrites the buffers

  // ---- fc2 B-fragments from fc2_w (L2-resident), hi/lo split --------------
  // B-frag: col(lane&15)=o, k=(lane>>4)*8+j
  int osafe = (lrow < 10) ? lrow : 9;
  bf16x8 whi[4], wlo[4];
#pragma unroll
  for (int s2 = 0; s2 < 4; ++s2) {
    f32x4 w0 = *(const f32x4*)(fc2_w + osafe * NCOLS + s2 * 32 + lgrp * 8);
    f32x4 w1 = *(const f32x4*)(fc2_w + osafe * NCOLS + s2 * 32 + lgrp * 8 + 4);
    if (lrow >= 10) { w0 = (f32x4){0.f,0.f,0.f,0.f}; w1 = (f32x4){0.f,0.f,0.f,0.f}; }
    split8(w0, w1, whi[s2], wlo[s2]);
  }
  float b2 = (lrow < 10) ? fc2_b[lrow] : 0.f;
  float bcol[NT];
#pragma unroll
  for (int n = 0; n < NT; ++n) bcol[n] = fc1_b[n * 16 + lrow];

  // ---- epilogue in two 16-row chunks: bias+relu -> LDS -> fc2 MFMA --------
  // fc1 C/D layout (m89): col = lane&15, row = (lane>>4)*4 + reg_idx.
  // hsh[wave] is per-wave private: same-wave LDS RAW handled by lgkmcnt.
#pragma unroll
  for (int m2 = 0; m2 < 2; ++m2) {
#pragma unroll
    for (int n = 0; n < NT; ++n) {
      int col = n * 16 + lrow;
#pragma unroll
      for (int ri = 0; ri < 4; ++ri) {
        int rl = lgrp * 4 + ri;
        hsh[wave][rl][col] = fmaxf(acc[m2][n][ri] + bcol[n], 0.f);
      }
    }
    f32x4 acc2 = (f32x4){0.f, 0.f, 0.f, 0.f};
    const float* hr = &hsh[wave][lrow][0];
#pragma unroll
    for (int s2 = 0; s2 < 4; ++s2) {
      f32x4 h0 = *(const f32x4*)(hr + s2 * 32 + lgrp * 8);
      f32x4 h1 = *(const f32x4*)(hr + s2 * 32 + lgrp * 8 + 4);
      bf16x8 ahi, alo; split8(h0, h1, ahi, alo);
      acc2 = __builtin_amdgcn_mfma_f32_16x16x32_bf16(ahi, whi[s2], acc2, 0, 0, 0);
      acc2 = __builtin_amdgcn_mfma_f32_16x16x32_bf16(ahi, wlo[s2], acc2, 0, 0, 0);
      acc2 = __builtin_amdgcn_mfma_f32_16x16x32_bf16(alo, whi[s2], acc2, 0, 0, 0);
    }
    // D layout: col(lane&15)=o, row=(lane>>4)*4+reg -> rows m2*16+lgrp*4+ri
    if (lrow < 10) {
#pragma unroll
      for (int ri = 0; ri < 4; ++ri)
        out[(wrow0 + m2 * 16 + lgrp * 4 + ri) * 10 + lrow] = acc2[ri] + b2;
    }
  }
}

extern "C" void kernel_launch(void* const* d_in, const int* in_sizes, int n_in,
                              void* d_out, int out_size, void* d_ws, size_t ws_size,
                              hipStream_t stream) {
  const float* x      = (const float*)d_in[0];
  const float* conv_w = (const float*)d_in[1];
  const float* fc1_w  = (const float*)d_in[2];
  const float* fc1_b  = (const float*)d_in[3];
  const float* fc2_w  = (const float*)d_in[4];
  const float* fc2_b  = (const float*)d_in[5];
  float* outp = (float*)d_out;
  __bf16* wfrag = (__bf16*)d_ws;                // needs 25*8*64*8*2 B = 200 KiB

  int Btotal = in_sizes[0] / KDIM;              // 65536
  int prep_threads = NSTEPS * NT * 64;          // 12800

  hipLaunchKernelGGL(prep_weff, dim3((prep_threads + 255) / 256), dim3(256), 0, stream,
                     conv_w, fc1_w, wfrag);
  hipLaunchKernelGGL(fused_mlp, dim3(Btotal / ROWS_PER_BLOCK), dim3(256), 0, stream,
                     x, wfrag, fc1_b, fc2_w, fc2_b, outp);
}

// Round 8
// 49.214 us; speedup vs baseline: 7.9645x; 1.0518x over previous
//
#include <hip/hip_runtime.h>

typedef __bf16 bf16x8 __attribute__((ext_vector_type(8)));
typedef float  f32x4  __attribute__((ext_vector_type(4)));

#define KDIM    784
#define KSTEP   32
#define NSTEPS  25          // ceil(784/32) -> K padded to 800
#define NCOLS   128
#define NT      8           // 128 / 16 col-tiles
#define WAVES   4
#define ROWS_PER_WAVE 32
#define ROWS_PER_BLOCK (WAVES * ROWS_PER_WAVE)   // 128
#define STAGE_BYTES 16384   // 2 k-steps of B-frags: 2 * 8 frags * 64 lanes * 16 B
#define HSH_PAD 132
#define HCHUNK  16          // fc2 processes 16 rows per m-chunk

// ---------------------------------------------------------------------------
// Prep: Weff[j,k] = sum_{u,v} conv_w[u,v] * fc1_w[j,(r-u)*26+(c-v)], stored as
// bf16 MFMA B-fragments: wfrag[((s*NT + n)*64 + lane)*8 + j] holds
// Weff[col = n*16 + (lane&15)][k = s*32 + (lane>>4)*8 + j]   (0 if k >= 784).
// 200 blocks x 64 threads (1 wave/block): spreads the latency-bound scattered
// fc1_w reads over 200 CUs instead of 50 (was 50 x 256). Same 12800 threads,
// byte-identical output.
// ---------------------------------------------------------------------------
__global__ __launch_bounds__(64) void prep_weff(
    const float* __restrict__ conv_w,
    const float* __restrict__ fc1_w,
    __bf16* __restrict__ wfrag)
{
  int idx = blockIdx.x * 64 + threadIdx.x;      // 200*64 = 12800 exactly
  if (idx >= NSTEPS * NT * 64) return;
  int lane = idx & 63;
  int n    = (idx >> 6) & (NT - 1);
  int s    = idx >> 9;
  int col  = n * 16 + (lane & 15);
  int kb   = s * KSTEP + (lane >> 4) * 8;
  bf16x8 o;
#pragma unroll
  for (int j = 0; j < 8; ++j) {
    int k = kb + j;
    float v = 0.f;
    if (k < KDIM) {
      int r = k / 28, c = k % 28;
#pragma unroll
      for (int u = 0; u < 3; ++u)
#pragma unroll
        for (int w = 0; w < 3; ++w) {
          int p = r - u, q = c - w;
          if (p >= 0 && p < 26 && q >= 0 && q < 26)
            v = fmaf(conv_w[u * 3 + w], fc1_w[col * 676 + p * 26 + q], v);
        }
    }
    o[j] = (__bf16)v;
  }
  reinterpret_cast<bf16x8*>(wfrag)[idx] = o;
}

__device__ __forceinline__ bf16x8 pack8(f32x4 lo, f32x4 hi) {
  bf16x8 r;
  r[0] = (__bf16)lo[0]; r[1] = (__bf16)lo[1];
  r[2] = (__bf16)lo[2]; r[3] = (__bf16)lo[3];
  r[4] = (__bf16)hi[0]; r[5] = (__bf16)hi[1];
  r[6] = (__bf16)hi[2]; r[7] = (__bf16)hi[3];
  return r;
}

// Split 8 fp32 into bf16 hi + bf16 residual lo (hi+lo reproduces fp32 to ~2^-17)
__device__ __forceinline__ void split8(f32x4 a, f32x4 b, bf16x8& hi, bf16x8& lo) {
#pragma unroll
  for (int j = 0; j < 4; ++j) {
    __bf16 h = (__bf16)a[j]; hi[j] = h; lo[j] = (__bf16)(a[j] - (float)h);
  }
#pragma unroll
  for (int j = 0; j < 4; ++j) {
    __bf16 h = (__bf16)b[j]; hi[4 + j] = h; lo[4 + j] = (__bf16)(b[j] - (float)h);
  }
}

// Async global->LDS copy of one B-frag stage slice. dest is linear
// (wave-uniform base + lane*16) which matches the frag consumption layout.
__device__ __forceinline__ void stage_issue(
    const __bf16* __restrict__ wfrag, unsigned char* dstbuf,
    int stage, int wave, int lane, int nchunks)
{
#pragma unroll
  for (int c = 0; c < 4; ++c) {
    int cw = wave * 4 + c;
    if (cw < nchunks) {
      const unsigned char* src =
          (const unsigned char*)wfrag + (size_t)stage * STAGE_BYTES + cw * 1024 + lane * 16;
      unsigned char* dst = dstbuf + cw * 1024 + lane * 16;
      __builtin_amdgcn_global_load_lds(
          (const __attribute__((address_space(1))) unsigned int*)src,
          (__attribute__((address_space(3))) unsigned int*)dst,
          16, 0, 0);
    }
  }
}

// ---------------------------------------------------------------------------
// Main (best-measured V2 structure, byte-identical): per block 4 waves x 32
// rows = 128 rows, all 128 h-columns via MFMA. B-frags double-buffered in
// LDS; x software-pipelined one stage ahead in registers; fc2 (128->10) via
// hi/lo-split bf16 MFMA in two 16-row chunks (hsh 16 rows/wave -> 33 KB LDS).
// ---------------------------------------------------------------------------
__global__ __launch_bounds__(256, 3) void fused_mlp(
    const float*  __restrict__ x,
    const __bf16* __restrict__ wfrag,
    const float*  __restrict__ fc1_b,
    const float*  __restrict__ fc2_w,
    const float*  __restrict__ fc2_b,
    float*        __restrict__ out)
{
  // 33 KiB: per-wave 16-row fc2 chunk buffers; first 32 KiB double as the two
  // B-frag staging buffers (dead before hsh is first written; barrier-separated).
  __shared__ __align__(16) unsigned char smem[WAVES * HCHUNK * HSH_PAD * 4];
  float (*hsh)[HCHUNK][HSH_PAD] =
      reinterpret_cast<float (*)[HCHUNK][HSH_PAD]>(smem);

  int tid  = threadIdx.x;
  int wave = tid >> 6, lane = tid & 63;
  int lrow = lane & 15;      // A row within 16-tile / B col within 16-tile
  int lgrp = lane >> 4;      // k sub-group
  long wrow0 = (long)blockIdx.x * ROWS_PER_BLOCK + wave * ROWS_PER_WAVE;

  const float* xr0 = x + (wrow0 + lrow) * KDIM;
  const float* xr1 = xr0 + 16 * KDIM;

  f32x4 acc[2][NT];
#pragma unroll
  for (int m = 0; m < 2; ++m)
#pragma unroll
    for (int n = 0; n < NT; ++n) acc[m][n] = (f32x4){0.f, 0.f, 0.f, 0.f};

  // x pipeline registers: one full stage (2 k-steps) ahead
  f32x4 xv[8];
#define LOAD_STAGE(T)                                          \
  {                                                            \
    int k0 = (2 * (T)) * KSTEP + lgrp * 8;                     \
    xv[0] = *(const f32x4*)(xr0 + k0);                         \
    xv[1] = *(const f32x4*)(xr0 + k0 + 4);                     \
    xv[2] = *(const f32x4*)(xr1 + k0);                         \
    xv[3] = *(const f32x4*)(xr1 + k0 + 4);                     \
    xv[4] = *(const f32x4*)(xr0 + k0 + KSTEP);                 \
    xv[5] = *(const f32x4*)(xr0 + k0 + KSTEP + 4);             \
    xv[6] = *(const f32x4*)(xr1 + k0 + KSTEP);                 \
    xv[7] = *(const f32x4*)(xr1 + k0 + KSTEP + 4);             \
  }

  // ---- prologue: stage 0 B-frags + stage 0 x ------------------------------
  stage_issue(wfrag, smem, 0, wave, lane, 16);
  LOAD_STAGE(0);
  int cur = 0;

  // ---- K loop: 12 stages of 2 steps (s=0..23); tail (s=24) after ----------
  for (int t = 0; t < 12; ++t) {
    __syncthreads();   // stage(t) B-frags landed; x(t) regs arrived (vmcnt drain)
    stage_issue(wfrag, smem + (cur ^ 1) * STAGE_BYTES, t + 1, wave, lane,
                (t < 11) ? 16 : 8);

    // pack current-stage A fragments, freeing xv for the next prefetch
    bf16x8 a00 = pack8(xv[0], xv[1]), a01 = pack8(xv[2], xv[3]);
    bf16x8 a10 = pack8(xv[4], xv[5]), a11 = pack8(xv[6], xv[7]);

    // prefetch x for stage t+1 (tail: only k<784 lanes real, rest zero)
    if (t < 11) {
      LOAD_STAGE(t + 1);
    } else {
      if (lgrp < 2) {
        int k = (NSTEPS - 1) * KSTEP + lgrp * 8;   // 768 or 776
        xv[0] = *(const f32x4*)(xr0 + k);
        xv[1] = *(const f32x4*)(xr0 + k + 4);
        xv[2] = *(const f32x4*)(xr1 + k);
        xv[3] = *(const f32x4*)(xr1 + k + 4);
      } else {
        xv[0] = (f32x4){0.f,0.f,0.f,0.f}; xv[1] = (f32x4){0.f,0.f,0.f,0.f};
        xv[2] = (f32x4){0.f,0.f,0.f,0.f}; xv[3] = (f32x4){0.f,0.f,0.f,0.f};
      }
    }

    const bf16x8* bp = (const bf16x8*)(smem + cur * STAGE_BYTES) + lane;
    {
      bf16x8 bf[NT];
#pragma unroll
      for (int n = 0; n < NT; ++n) bf[n] = bp[n * 64];
#pragma unroll
      for (int n = 0; n < NT; ++n) {
        acc[0][n] = __builtin_amdgcn_mfma_f32_16x16x32_bf16(a00, bf[n], acc[0][n], 0, 0, 0);
        acc[1][n] = __builtin_amdgcn_mfma_f32_16x16x32_bf16(a01, bf[n], acc[1][n], 0, 0, 0);
      }
    }
    {
      bf16x8 bf[NT];
#pragma unroll
      for (int n = 0; n < NT; ++n) bf[n] = bp[512 + n * 64];
#pragma unroll
      for (int n = 0; n < NT; ++n) {
        acc[0][n] = __builtin_amdgcn_mfma_f32_16x16x32_bf16(a10, bf[n], acc[0][n], 0, 0, 0);
        acc[1][n] = __builtin_amdgcn_mfma_f32_16x16x32_bf16(a11, bf[n], acc[1][n], 0, 0, 0);
      }
    }
    cur ^= 1;
  }

  // ---- tail step s = 24 (x already in xv[0..3]) ---------------------------
  __syncthreads();   // tail stage landed
  {
    bf16x8 a0 = pack8(xv[0], xv[1]);
    bf16x8 a1 = pack8(xv[2], xv[3]);
    const bf16x8* bp = (const bf16x8*)(smem + cur * STAGE_BYTES) + lane;
#pragma unroll
    for (int n = 0; n < NT; ++n) {
      bf16x8 b = bp[n * 64];
      acc[0][n] = __builtin_amdgcn_mfma_f32_16x16x32_bf16(a0, b, acc[0][n], 0, 0, 0);
      acc[1][n] = __builtin_amdgcn_mfma_f32_16x16x32_bf16(a1, b, acc[1][n], 0, 0, 0);
    }
  }
  __syncthreads();   // all staging reads done before hsh overwrites the buffers

  // ---- fc2 B-fragments from fc2_w (L2-resident), hi/lo split --------------
  // B-frag: col(lane&15)=o, k=(lane>>4)*8+j
  int osafe = (lrow < 10) ? lrow : 9;
  bf16x8 whi[4], wlo[4];
#pragma unroll
  for (int s2 = 0; s2 < 4; ++s2) {
    f32x4 w0 = *(const f32x4*)(fc2_w + osafe * NCOLS + s2 * 32 + lgrp * 8);
    f32x4 w1 = *(const f32x4*)(fc2_w + osafe * NCOLS + s2 * 32 + lgrp * 8 + 4);
    if (lrow >= 10) { w0 = (f32x4){0.f,0.f,0.f,0.f}; w1 = (f32x4){0.f,0.f,0.f,0.f}; }
    split8(w0, w1, whi[s2], wlo[s2]);
  }
  float b2 = (lrow < 10) ? fc2_b[lrow] : 0.f;
  float bcol[NT];
#pragma unroll
  for (int n = 0; n < NT; ++n) bcol[n] = fc1_b[n * 16 + lrow];

  // ---- epilogue in two 16-row chunks: bias+relu -> LDS -> fc2 MFMA --------
  // fc1 C/D layout (m89): col = lane&15, row = (lane>>4)*4 + reg_idx.
  // hsh[wave] is per-wave private: same-wave LDS RAW handled by lgkmcnt.
#pragma unroll
  for (int m2 = 0; m2 < 2; ++m2) {
#pragma unroll
    for (int n = 0; n < NT; ++n) {
      int col = n * 16 + lrow;
#pragma unroll
      for (int ri = 0; ri < 4; ++ri) {
        int rl = lgrp * 4 + ri;
        hsh[wave][rl][col] = fmaxf(acc[m2][n][ri] + bcol[n], 0.f);
      }
    }
    f32x4 acc2 = (f32x4){0.f, 0.f, 0.f, 0.f};
    const float* hr = &hsh[wave][lrow][0];
#pragma unroll
    for (int s2 = 0; s2 < 4; ++s2) {
      f32x4 h0 = *(const f32x4*)(hr + s2 * 32 + lgrp * 8);
      f32x4 h1 = *(const f32x4*)(hr + s2 * 32 + lgrp * 8 + 4);
      bf16x8 ahi, alo; split8(h0, h1, ahi, alo);
      acc2 = __builtin_amdgcn_mfma_f32_16x16x32_bf16(ahi, whi[s2], acc2, 0, 0, 0);
      acc2 = __builtin_amdgcn_mfma_f32_16x16x32_bf16(ahi, wlo[s2], acc2, 0, 0, 0);
      acc2 = __builtin_amdgcn_mfma_f32_16x16x32_bf16(alo, whi[s2], acc2, 0, 0, 0);
    }
    // D layout: col(lane&15)=o, row=(lane>>4)*4+reg -> rows m2*16+lgrp*4+ri
    if (lrow < 10) {
#pragma unroll
      for (int ri = 0; ri < 4; ++ri)
        out[(wrow0 + m2 * 16 + lgrp * 4 + ri) * 10 + lrow] = acc2[ri] + b2;
    }
  }
}

extern "C" void kernel_launch(void* const* d_in, const int* in_sizes, int n_in,
                              void* d_out, int out_size, void* d_ws, size_t ws_size,
                              hipStream_t stream) {
  const float* x      = (const float*)d_in[0];
  const float* conv_w = (const float*)d_in[1];
  const float* fc1_w  = (const float*)d_in[2];
  const float* fc1_b  = (const float*)d_in[3];
  const float* fc2_w  = (const float*)d_in[4];
  const float* fc2_b  = (const float*)d_in[5];
  float* outp = (float*)d_out;
  __bf16* wfrag = (__bf16*)d_ws;                // needs 25*8*64*8*2 B = 200 KiB

  int Btotal = in_sizes[0] / KDIM;              // 65536
  int prep_threads = NSTEPS * NT * 64;          // 12800

  hipLaunchKernelGGL(prep_weff, dim3(prep_threads / 64), dim3(64), 0, stream,
                     conv_w, fc1_w, wfrag);
  hipLaunchKernelGGL(fused_mlp, dim3(Btotal / ROWS_PER_BLOCK), dim3(256), 0, stream,
                     x, wfrag, fc1_b, fc2_w, fc2_b, outp);
}

// Round 9
// 46.943 us; speedup vs baseline: 8.3497x; 1.0484x over previous
//
#include <hip/hip_runtime.h>

typedef __bf16 bf16x8 __attribute__((ext_vector_type(8)));
typedef float  f32x4  __attribute__((ext_vector_type(4)));

#define KDIM    784
#define KSTEP   32
#define NSTEPS  25          // ceil(784/32) -> K padded to 800
#define NCOLS   128
#define NT      8           // 128 / 16 col-tiles
#define WAVES   4
#define ROWS_PER_WAVE 32
#define ROWS_PER_BLOCK (WAVES * ROWS_PER_WAVE)   // 128
#define XSTEP_BYTES 16384   // one k-step of x: 128 rows x 128 B
#define WSTEP_BYTES 8192    // one k-step of B-frags: 8 frags * 64 lanes * 16 B
#define HSH_PAD 132
#define HCHUNK  16          // fc2 processes 16 rows per m-chunk
// LDS: [0,32K) x dbuf, [32K,48K) wfrag dbuf; hsh (33 KB) aliases from 0.

// ---------------------------------------------------------------------------
// Prep: Weff[j,k] = sum_{u,v} conv_w[u,v] * fc1_w[j,(r-u)*26+(c-v)], stored as
// bf16 MFMA B-fragments: wfrag[((s*NT + n)*64 + lane)*8 + j] holds
// Weff[col = n*16 + (lane&15)][k = s*32 + (lane>>4)*8 + j]   (0 if k >= 784).
// 200 blocks x 64 threads (R8 win: spreads latency-bound reads over 200 CUs).
// ---------------------------------------------------------------------------
__global__ __launch_bounds__(64) void prep_weff(
    const float* __restrict__ conv_w,
    const float* __restrict__ fc1_w,
    __bf16* __restrict__ wfrag)
{
  int idx = blockIdx.x * 64 + threadIdx.x;      // 200*64 = 12800 exactly
  if (idx >= NSTEPS * NT * 64) return;
  int lane = idx & 63;
  int n    = (idx >> 6) & (NT - 1);
  int s    = idx >> 9;
  int col  = n * 16 + (lane & 15);
  int kb   = s * KSTEP + (lane >> 4) * 8;
  bf16x8 o;
#pragma unroll
  for (int j = 0; j < 8; ++j) {
    int k = kb + j;
    float v = 0.f;
    if (k < KDIM) {
      int r = k / 28, c = k % 28;
#pragma unroll
      for (int u = 0; u < 3; ++u)
#pragma unroll
        for (int w = 0; w < 3; ++w) {
          int p = r - u, q = c - w;
          if (p >= 0 && p < 26 && q >= 0 && q < 26)
            v = fmaf(conv_w[u * 3 + w], fc1_w[col * 676 + p * 26 + q], v);
        }
    }
    o[j] = (__bf16)v;
  }
  reinterpret_cast<bf16x8*>(wfrag)[idx] = o;
}

__device__ __forceinline__ bf16x8 pack8(f32x4 lo, f32x4 hi) {
  bf16x8 r;
  r[0] = (__bf16)lo[0]; r[1] = (__bf16)lo[1];
  r[2] = (__bf16)lo[2]; r[3] = (__bf16)lo[3];
  r[4] = (__bf16)hi[0]; r[5] = (__bf16)hi[1];
  r[6] = (__bf16)hi[2]; r[7] = (__bf16)hi[3];
  return r;
}

// Split 8 fp32 into bf16 hi + bf16 residual lo (hi+lo reproduces fp32 to ~2^-17)
__device__ __forceinline__ void split8(f32x4 a, f32x4 b, bf16x8& hi, bf16x8& lo) {
#pragma unroll
  for (int j = 0; j < 4; ++j) {
    __bf16 h = (__bf16)a[j]; hi[j] = h; lo[j] = (__bf16)(a[j] - (float)h);
  }
#pragma unroll
  for (int j = 0; j < 4; ++j) {
    __bf16 h = (__bf16)b[j]; hi[4 + j] = h; lo[4 + j] = (__bf16)(b[j] - (float)h);
  }
}

// Copy one k-step of x (dense lines, pre-swizzled source) + wfrag into LDS.
// x: 16 chunks of {8 rows x 128 B}; 8 consecutive lanes cover one row's 128 B
// chunk fully (16 dense 64B lines per instruction vs 32 half-used lines in the
// register path). Source byte pre-swizzled by ((row&7)<<4) so the linear LDS
// dest holds the XOR-swizzled layout (m173 pattern); frag ds_reads use the
// same XOR -> conflict-free.
__device__ __forceinline__ void stage_copy(
    const float* __restrict__ xrowbase, const __bf16* __restrict__ wfrag,
    unsigned char* smem, int buf, int t, int wave, int lane)
{
  unsigned char* xdst = smem + buf * XSTEP_BYTES;
  int sb = ((lane & 7) * 16) ^ (((lane >> 3) & 7) << 4);   // swizzled byte-in-chunk
  int row_off = t * 128 + sb;
  if (row_off + 16 > KDIM * 4) row_off = 0;   // tail clamp; wfrag zeros kill k>=784
#pragma unroll
  for (int i = 0; i < 4; ++i) {
    int c = wave * 4 + i;                     // chunk = rows [c*8, c*8+8)
    const unsigned char* src =
        (const unsigned char*)(xrowbase + (size_t)(c * 8 + (lane >> 3)) * KDIM) + row_off;
    unsigned char* dst = xdst + c * 1024 + lane * 16;
    __builtin_amdgcn_global_load_lds(
        (const __attribute__((address_space(1))) unsigned int*)src,
        (__attribute__((address_space(3))) unsigned int*)dst, 16, 0, 0);
  }
  unsigned char* wdst = smem + 2 * XSTEP_BYTES + buf * WSTEP_BYTES;
  const unsigned char* wsrc = (const unsigned char*)wfrag + (size_t)t * WSTEP_BYTES;
#pragma unroll
  for (int i = 0; i < 2; ++i) {
    int c = wave * 2 + i;
    const unsigned char* src = wsrc + c * 1024 + lane * 16;
    unsigned char* dst = wdst + c * 1024 + lane * 16;
    __builtin_amdgcn_global_load_lds(
        (const __attribute__((address_space(1))) unsigned int*)src,
        (__attribute__((address_space(3))) unsigned int*)dst, 16, 0, 0);
  }
}

// ---------------------------------------------------------------------------
// Main: per block 4 waves x 32 rows = 128 rows, all 128 h-columns via MFMA.
// BOTH x and B-frags staged via global_load_lds (dense-line requests),
// double-buffered, 25 single-k-step stages (barrier count proven irrelevant,
// R7). A-fragments read from swizzled LDS (conflict-free). fc2 (128->10) via
// hi/lo-split bf16 MFMA in two 16-row chunks. MFMA order identical to prior
// rounds -> bit-identical accumulation.
// ---------------------------------------------------------------------------
__global__ __launch_bounds__(256, 2) void fused_mlp(
    const float*  __restrict__ x,
    const __bf16* __restrict__ wfrag,
    const float*  __restrict__ fc1_b,
    const float*  __restrict__ fc2_w,
    const float*  __restrict__ fc2_b,
    float*        __restrict__ out)
{
  __shared__ __align__(16) unsigned char smem[2 * XSTEP_BYTES + 2 * WSTEP_BYTES];
  float (*hsh)[HCHUNK][HSH_PAD] =
      reinterpret_cast<float (*)[HCHUNK][HSH_PAD]>(smem);   // 33 KB alias

  int tid  = threadIdx.x;
  int wave = tid >> 6, lane = tid & 63;
  int lrow = lane & 15;      // A row within 16-tile / B col within 16-tile
  int lgrp = lane >> 4;      // k sub-group
  long wrow0 = (long)blockIdx.x * ROWS_PER_BLOCK + wave * ROWS_PER_WAVE;
  const float* xrowbase = x + (long)blockIdx.x * ROWS_PER_BLOCK * KDIM;

  f32x4 acc[2][NT];
#pragma unroll
  for (int m = 0; m < 2; ++m)
#pragma unroll
    for (int n = 0; n < NT; ++n) acc[m][n] = (f32x4){0.f, 0.f, 0.f, 0.f};

  // fragment LDS addresses (constant across stages except buffer base)
  int base0 = (wave * 32 + lrow) * 128;
  int base1 = base0 + 16 * 128;
  int swz   = (lrow & 7) << 4;
  int sb0   = (lgrp * 32) ^ swz;
  int sb1   = (lgrp * 32 + 16) ^ swz;

  // ---- prologue: stage 0 ---------------------------------------------------
  stage_copy(xrowbase, wfrag, smem, 0, 0, wave, lane);

  // ---- K loop: 25 single-k-step stages ------------------------------------
  for (int t = 0; t < NSTEPS; ++t) {
    __syncthreads();   // stage(t) landed (vmcnt drain); stage(t-1) reads done
    if (t < NSTEPS - 1)
      stage_copy(xrowbase, wfrag, smem, (t + 1) & 1, t + 1, wave, lane);

    int buf = t & 1;
    const unsigned char* xb = smem + buf * XSTEP_BYTES;
    const bf16x8* bp =
        (const bf16x8*)(smem + 2 * XSTEP_BYTES + buf * WSTEP_BYTES) + lane;

    f32x4 x00 = *(const f32x4*)(xb + base0 + sb0);
    f32x4 x01 = *(const f32x4*)(xb + base0 + sb1);
    f32x4 x10 = *(const f32x4*)(xb + base1 + sb0);
    f32x4 x11 = *(const f32x4*)(xb + base1 + sb1);
    bf16x8 a0 = pack8(x00, x01);
    bf16x8 a1 = pack8(x10, x11);

    bf16x8 bf[NT];
#pragma unroll
    for (int n = 0; n < NT; ++n) bf[n] = bp[n * 64];
#pragma unroll
    for (int n = 0; n < NT; ++n) {
      acc[0][n] = __builtin_amdgcn_mfma_f32_16x16x32_bf16(a0, bf[n], acc[0][n], 0, 0, 0);
      acc[1][n] = __builtin_amdgcn_mfma_f32_16x16x32_bf16(a1, bf[n], acc[1][n], 0, 0, 0);
    }
  }
  __syncthreads();   // all staging reads done before hsh overwrites the buffers

  // ---- fc2 B-fragments from fc2_w (L2-resident), hi/lo split --------------
  // B-frag: col(lane&15)=o, k=(lane>>4)*8+j
  int osafe = (lrow < 10) ? lrow : 9;
  bf16x8 whi[4], wlo[4];
#pragma unroll
  for (int s2 = 0; s2 < 4; ++s2) {
    f32x4 w0 = *(const f32x4*)(fc2_w + osafe * NCOLS + s2 * 32 + lgrp * 8);
    f32x4 w1 = *(const f32x4*)(fc2_w + osafe * NCOLS + s2 * 32 + lgrp * 8 + 4);
    if (lrow >= 10) { w0 = (f32x4){0.f,0.f,0.f,0.f}; w1 = (f32x4){0.f,0.f,0.f,0.f}; }
    split8(w0, w1, whi[s2], wlo[s2]);
  }
  float b2 = (lrow < 10) ? fc2_b[lrow] : 0.f;
  float bcol[NT];
#pragma unroll
  for (int n = 0; n < NT; ++n) bcol[n] = fc1_b[n * 16 + lrow];

  // ---- epilogue in two 16-row chunks: bias+relu -> LDS -> fc2 MFMA --------
  // fc1 C/D layout (m89): col = lane&15, row = (lane>>4)*4 + reg_idx.
  // hsh[wave] is per-wave private: same-wave LDS RAW handled by lgkmcnt.
#pragma unroll
  for (int m2 = 0; m2 < 2; ++m2) {
#pragma unroll
    for (int n = 0; n < NT; ++n) {
      int col = n * 16 + lrow;
#pragma unroll
      for (int ri = 0; ri < 4; ++ri) {
        int rl = lgrp * 4 + ri;
        hsh[wave][rl][col] = fmaxf(acc[m2][n][ri] + bcol[n], 0.f);
      }
    }
    f32x4 acc2 = (f32x4){0.f, 0.f, 0.f, 0.f};
    const float* hr = &hsh[wave][lrow][0];
#pragma unroll
    for (int s2 = 0; s2 < 4; ++s2) {
      f32x4 h0 = *(const f32x4*)(hr + s2 * 32 + lgrp * 8);
      f32x4 h1 = *(const f32x4*)(hr + s2 * 32 + lgrp * 8 + 4);
      bf16x8 ahi, alo; split8(h0, h1, ahi, alo);
      acc2 = __builtin_amdgcn_mfma_f32_16x16x32_bf16(ahi, whi[s2], acc2, 0, 0, 0);
      acc2 = __builtin_amdgcn_mfma_f32_16x16x32_bf16(ahi, wlo[s2], acc2, 0, 0, 0);
      acc2 = __builtin_amdgcn_mfma_f32_16x16x32_bf16(alo, whi[s2], acc2, 0, 0, 0);
    }
    // D layout: col(lane&15)=o, row=(lane>>4)*4+reg -> rows m2*16+lgrp*4+ri
    if (lrow < 10) {
#pragma unroll
      for (int ri = 0; ri < 4; ++ri)
        out[(wrow0 + m2 * 16 + lgrp * 4 + ri) * 10 + lrow] = acc2[ri] + b2;
    }
  }
}

extern "C" void kernel_launch(void* const* d_in, const int* in_sizes, int n_in,
                              void* d_out, int out_size, void* d_ws, size_t ws_size,
                              hipStream_t stream) {
  const float* x      = (const float*)d_in[0];
  const float* conv_w = (const float*)d_in[1];
  const float* fc1_w  = (const float*)d_in[2];
  const float* fc1_b  = (const float*)d_in[3];
  const float* fc2_w  = (const float*)d_in[4];
  const float* fc2_b  = (const float*)d_in[5];
  float* outp = (float*)d_out;
  __bf16* wfrag = (__bf16*)d_ws;                // needs 25*8*64*8*2 B = 200 KiB

  int Btotal = in_sizes[0] / KDIM;              // 65536
  int prep_threads = NSTEPS * NT * 64;          // 12800

  hipLaunchKernelGGL(prep_weff, dim3(prep_threads / 64), dim3(64), 0, stream,
                     conv_w, fc1_w, wfrag);
  hipLaunchKernelGGL(fused_mlp, dim3(Btotal / ROWS_PER_BLOCK), dim3(256), 0, stream,
                     x, wfrag, fc1_b, fc2_w, fc2_b, outp);
}